// Round 32
// baseline (43.754 us; speedup 1.0000x reference)
//
#include <hip/hip_runtime.h>
#include <hip/hip_bf16.h>
#include <hip/hip_fp16.h>
#include <cstddef>

#define BN 4096
#define DD 128
#define NSTEPS 100
#define PTILE 128
#define PLSTR 136   // poscls LDS row stride (padded)
#define GRID_T 32
#define NOFF 496    // strictly-upper tile pairs (ti<tj)
#define NBLK 264    // neg: 2 units per block (528 units)
#define NREPC2 8    // cdf float2 replicas (stride 101)

typedef __attribute__((ext_vector_type(8))) short bf16x8;
typedef __attribute__((ext_vector_type(4))) float f32x4;

__device__ __forceinline__ void faddf(float* p, float v) { unsafeAtomicAdd(p, v); }

// ws ctl: gPos[100] gLoss[32] gCnt[32] gDone gDoneP  (166 words) | gCdf[100]
#define ZERON 166

// ---------------- normalize + convert to bf16 + zero control block ----------------
__global__ __launch_bounds__(256) void hl_normalize(const float* __restrict__ emb,
                                                    ushort* __restrict__ out,
                                                    float* __restrict__ zero_blk) {
    if (blockIdx.x == 0 && threadIdx.x < ZERON) zero_blk[threadIdx.x] = 0.f;
    int w = threadIdx.x >> 6;
    int lane = threadIdx.x & 63;
    int row = (blockIdx.x << 2) + w;
    const float2 v = *(const float2*)(emb + (size_t)row * DD + 2 * lane);
    float ss = v.x * v.x + v.y * v.y;
    #pragma unroll
    for (int off = 32; off > 0; off >>= 1) ss += __shfl_xor(ss, off);
    float inv = 1.0f / sqrtf(ss);
    __hip_bfloat16 b0 = __float2bfloat16(v.x * inv);
    __hip_bfloat16 b1 = __float2bfloat16(v.y * inv);
    ushort2 pk;
    pk.x = *(ushort*)&b0;
    pk.y = *(ushort*)&b1;
    *(ushort2*)(out + (size_t)row * DD + 2 * lane) = pk;
}

// ---------------- POS histogram: per-class MFMA gram; last block builds cdf ----------
// r32: per-pair LDS fp-atomics (~1680 lane-ops/block x 6.3cyc = ~4.4us) replaced
// by non-atomic per-thread fp16 columns (r10/r14-validated) + staggered reduce.
// Also: si==sj tiles alias Bs=As (skip duplicate gather staging).
__global__ __launch_bounds__(256) void hl_poscls(const ushort* __restrict__ nemb,
                                                 const int* __restrict__ cls,
                                                 float* __restrict__ gPos,
                                                 unsigned int* __restrict__ gDoneP,
                                                 float* __restrict__ gCdf) {
    const int c = blockIdx.x;
    __shared__ int idx[256];
    __shared__ ushort As[64 * PLSTR];         // 17408 B
    __shared__ ushort Bs[64 * PLSTR];         // 17408 B
    __shared__ _Float16 hallh[NSTEPS * 256];  // 51200 B, per-thread columns
    __shared__ float scanb[128];
    __shared__ int mCnt;
    __shared__ int lastFlag;
    uint* hall32 = (uint*)hallh;
    const int tid = threadIdx.x;

    if (tid == 0) mCnt = 0;
    #pragma unroll 8
    for (int i = tid; i < NSTEPS * 128; i += 256) hall32[i] = 0u;
    __syncthreads();

    // order-free compaction (histogram is pair-set-invariant; r30/r31-validated)
    for (int i = tid; i < BN; i += 256)
        if (cls[i] == c) { int p = atomicAdd(&mCnt, 1); if (p < 256) idx[p] = i; }
    __syncthreads();
    const int m = mCnt > 256 ? 256 : mCnt;
    const int nt = (m + 63) >> 6;

    constexpr float INVSTEP = 49.5f;
    constexpr float CLIPV = 1.0f - 1e-6f;

    const int lane = tid & 63;
    const int wv = tid >> 6;
    const int lr = lane & 15;
    const int kg = lane >> 4;

    for (int si = 0; si < nt; ++si) {
        for (int sj = si; sj < nt; ++sj) {
            const bool same = (sj == si);
            __syncthreads();
            #pragma unroll
            for (int it = 0; it < 2; ++it) {
                int q = it * 256 + tid;       // 0..511: 32 rows per pass
                int row = q >> 4;             // rows staged in 4 passes of 32? no:
                // 64 rows x 16 chunks = 1024 slots; with Bs maybe skipped do 2 loops
                (void)row;
            }
            // stage As (64 rows x 16 chunks of 16B = 1024 slots, 4 iters)
            #pragma unroll
            for (int it = 0; it < 4; ++it) {
                int q = it * 256 + tid;
                int row = q >> 4;
                int ch = q & 15;
                int ga = si * 64 + row;
                int ra = idx[ga < m ? ga : 0];
                *(float4*)(&As[row * PLSTR + ch * 8]) =
                    *(const float4*)(nemb + (size_t)ra * DD + ch * 8);
            }
            if (!same) {
                #pragma unroll
                for (int it = 0; it < 4; ++it) {
                    int q = it * 256 + tid;
                    int row = q >> 4;
                    int ch = q & 15;
                    int gb = sj * 64 + row;
                    int rb = idx[gb < m ? gb : 0];
                    *(float4*)(&Bs[row * PLSTR + ch * 8]) =
                        *(const float4*)(nemb + (size_t)rb * DD + ch * 8);
                }
            }
            __syncthreads();

            const ushort* Bsel = same ? As : Bs;

            f32x4 zero4 = {0.f, 0.f, 0.f, 0.f};
            f32x4 pacc[4] = {zero4, zero4, zero4, zero4};
            #pragma unroll
            for (int ks = 0; ks < 4; ++ks) {
                bf16x8 af = *(const bf16x8*)(&As[(wv * 16 + lr) * PLSTR + ks * 32 + kg * 8]);
                #pragma unroll
                for (int fb = 0; fb < 4; ++fb) {
                    bf16x8 bf = *(const bf16x8*)(&Bsel[(fb * 16 + lr) * PLSTR + ks * 32 + kg * 8]);
                    pacc[fb] = __builtin_amdgcn_mfma_f32_16x16x32_bf16(af, bf, pacc[fb], 0, 0, 0);
                }
            }

            // epilogue: non-atomic per-thread fp16 columns (race-free: own tid col)
            #pragma unroll
            for (int fb = 0; fb < 4; ++fb) {
                const int gb = sj * 64 + fb * 16 + lr;
                #pragma unroll
                for (int j = 0; j < 4; ++j) {
                    const int ga = si * 64 + wv * 16 + kg * 4 + j;
                    const bool valid = (ga < gb) && (gb < m);
                    float s = pacc[fb][j];
                    s = fminf(fmaxf(s, -CLIPV), CLIPV);
                    float u = (s + CLIPV) * INVSTEP;
                    int jb = (int)u;
                    if (jb > 98) jb = 98;
                    float vm = valid ? 1.0f : 0.0f;
                    float w_hi = (u - (float)jb) * vm;
                    float w_lo = vm - w_hi;
                    int base = jb * 256 + tid;
                    _Float16 lo = hallh[base];
                    _Float16 hi = hallh[base + 256];
                    hallh[base] = lo + (_Float16)w_lo;
                    hallh[base + 256] = hi + (_Float16)w_hi;
                }
            }
        }
    }
    __syncthreads();

    // reduce columns (r14-validated staggered uint reads) -> 1 atomic per bin
    if (tid < NSTEPS) {
        const int b = tid;
        float ssum = 0.f;
        #pragma unroll 8
        for (int r = 0; r < 64; ++r) {
            uint u2 = hall32[b * 128 + ((r + b) & 127)];
            __half2 h2 = *(__half2*)&u2;
            ssum += __low2float(h2) + __high2float(h2);
        }
        if (ssum != 0.f) faddf(&gPos[b], ssum);
    } else if (tid >= 128 && tid < 128 + NSTEPS) {
        const int b = tid - 128;
        float ssum = 0.f;
        #pragma unroll 8
        for (int r = 64; r < 128; ++r) {
            uint u2 = hall32[b * 128 + ((r + b) & 127)];
            __half2 h2 = *(__half2*)&u2;
            ssum += __low2float(h2) + __high2float(h2);
        }
        if (ssum != 0.f) faddf(&gPos[b], ssum);
    }
    __threadfence();
    if (tid == 0) {
        unsigned int tk = atomicAdd(gDoneP, 1u);
        lastFlag = (tk == NSTEPS - 1);
    }
    __syncthreads();
    if (lastFlag) {
        float v = (tid < NSTEPS)
            ? __hip_atomic_load(&gPos[tid], __ATOMIC_RELAXED, __HIP_MEMORY_SCOPE_AGENT) : 0.f;
        if (tid < 128) scanb[tid] = v;
        __syncthreads();
        for (int off = 1; off < 128; off <<= 1) {
            float x = 0.f;
            if (tid < 128 && tid >= off) x = scanb[tid - off];
            __syncthreads();
            if (tid < 128) scanb[tid] += x;
            __syncthreads();
        }
        const float invsp = 1.0f / scanb[NSTEPS - 1];
        if (tid < NSTEPS) gCdf[tid] = scanb[tid] * invsp;
    }
}

// ---------------- NEG pass: 2-unit software-pipelined MFMA + cdf gather ----------
// stage(u+1) issued after MFMA(u); register epilogue hides the staging flight.
__global__ __launch_bounds__(256, 2) void hl_neg(const ushort* __restrict__ nemb,
                                                 const int* __restrict__ cls,
                                                 const float* __restrict__ gCdf,
                                                 float* __restrict__ gLoss,
                                                 float* __restrict__ gCnt,
                                                 unsigned int* __restrict__ gDone,
                                                 float* __restrict__ out) {
    __shared__ ushort As[PTILE * 128];
    __shared__ ushort Bs[PTILE * 128];
    __shared__ float2 cdf2[NREPC2 * 101];
    __shared__ float red[8];
    __shared__ int clsAb[2][PTILE], clsBb[2][PTILE];

    const int tid = threadIdx.x;
    const int lane = tid & 63;
    const int wid = tid >> 6;
    const int wr = wid >> 1, wc = wid & 1;
    const int lr = lane & 15;
    const int kg = lane >> 4;

    int tiU[2], tjU[2];
    #pragma unroll
    for (int u = 0; u < 2; ++u) {
        int id = blockIdx.x * 2 + u;
        if (id < NOFF) {
            int ti = 0, rem = id;
            while (rem >= GRID_T - 1 - ti) { rem -= GRID_T - 1 - ti; ++ti; }
            tiU[u] = ti; tjU[u] = ti + 1 + rem;
        } else {
            tiU[u] = tjU[u] = id - NOFF;
        }
    }

    for (int i = tid; i < NREPC2 * NSTEPS; i += 256) {
        int r = i / NSTEPS, b = i - r * NSTEPS;
        float c0 = gCdf[b];
        float c1 = gCdf[(b < NSTEPS - 1) ? b + 1 : NSTEPS - 1];
        float2 cd; cd.x = c0; cd.y = c1 - c0;
        cdf2[r * 101 + b] = cd;
    }

    constexpr float INVSTEP = 49.5f;
    constexpr float CLIPV = 1.0f - 1e-6f;
    const float2* crep2 = &cdf2[(lane & 7) * 101];
    const int li_base = wr * 64 + (kg << 2);
    const int lj_base = wc * 64 + lr;

    float lacc = 0.f, lcnt = 0.f;
    const int rloc = lane >> 4;
    const int pch = lane & 15;

    #define STAGE_UNIT(U)                                                            \
    {                                                                                \
        const int ti_ = tiU[U], tj_ = tjU[U];                                        \
        const bool dg_ = (ti_ == tj_);                                               \
        if (tid < PTILE) clsAb[(U) & 1][tid] = cls[ti_ * PTILE + tid];               \
        else             clsBb[(U) & 1][tid - PTILE] = cls[tj_ * PTILE + (tid - PTILE)]; \
        const ushort* Ag_ = nemb + (size_t)(ti_ * PTILE) * DD;                       \
        const ushort* Bg_ = nemb + (size_t)(tj_ * PTILE) * DD;                       \
        _Pragma("unroll")                                                            \
        for (int t = 0; t < 8; ++t) {                                                \
            int row = wid * 32 + t * 4 + rloc;                                       \
            int lch = pch ^ (row & 7);                                               \
            const ushort* ga = Ag_ + (size_t)row * DD + lch * 8;                     \
            ushort* la = &As[(wid * 32 + t * 4) * 128];                              \
            __builtin_amdgcn_global_load_lds(                                        \
                (const __attribute__((address_space(1))) void*)ga,                   \
                (__attribute__((address_space(3))) void*)la, 16, 0, 0);              \
        }                                                                            \
        if (!dg_) {                                                                  \
            _Pragma("unroll")                                                        \
            for (int t = 0; t < 8; ++t) {                                            \
                int row = wid * 32 + t * 4 + rloc;                                   \
                int lch = pch ^ (row & 7);                                           \
                const ushort* gb = Bg_ + (size_t)row * DD + lch * 8;                 \
                ushort* lb = &Bs[(wid * 32 + t * 4) * 128];                          \
                __builtin_amdgcn_global_load_lds(                                    \
                    (const __attribute__((address_space(1))) void*)gb,               \
                    (__attribute__((address_space(3))) void*)lb, 16, 0, 0);          \
            }                                                                        \
        }                                                                            \
    }

    STAGE_UNIT(0);

    #pragma unroll
    for (int u = 0; u < 2; ++u) {
        const bool diag = (tiU[u] == tjU[u]);

        __syncthreads();

        const ushort* Bsel = diag ? As : Bs;

        f32x4 zero4 = {0.f, 0.f, 0.f, 0.f};
        f32x4 acc[4][4];
        #pragma unroll
        for (int a = 0; a < 4; ++a)
            #pragma unroll
            for (int b = 0; b < 4; ++b) acc[a][b] = zero4;

        #pragma unroll
        for (int ks = 0; ks < 4; ++ks) {
            bf16x8 af[4], bfr[4];
            #pragma unroll
            for (int f = 0; f < 4; ++f) {
                int arow = wr * 64 + f * 16 + lr;
                int pca = ((ks << 2) | kg) ^ (arow & 7);
                af[f] = *(const bf16x8*)(&As[arow * 128 + pca * 8]);
                int brow = wc * 64 + f * 16 + lr;
                int pcb = ((ks << 2) | kg) ^ (brow & 7);
                bfr[f] = *(const bf16x8*)(&Bsel[brow * 128 + pcb * 8]);
            }
            #pragma unroll
            for (int fa = 0; fa < 4; ++fa)
                #pragma unroll
                for (int fb = 0; fb < 4; ++fb)
                    acc[fa][fb] = __builtin_amdgcn_mfma_f32_16x16x32_bf16(af[fa], bfr[fb], acc[fa][fb], 0, 0, 0);
        }

        __syncthreads();

        if (u == 0) STAGE_UNIT(1);

        const int* clsA_ = clsAb[u & 1];
        const int* clsB_ = diag ? clsAb[u & 1] : clsBb[u & 1];
        const bool offdiag = !diag;

        int ca[16];
        #pragma unroll
        for (int fa = 0; fa < 4; ++fa)
            #pragma unroll
            for (int j = 0; j < 4; ++j) ca[fa * 4 + j] = clsA_[li_base + fa * 16 + j];

        #pragma unroll
        for (int fb = 0; fb < 4; ++fb) {
            const int lj = lj_base + fb * 16;
            const int cb = clsB_[lj];
            #pragma unroll
            for (int fa = 0; fa < 4; ++fa) {
                const int li0 = li_base + fa * 16;
                f32x4 v = acc[fa][fb];
                #pragma unroll
                for (int j = 0; j < 4; ++j) {
                    const int li = li0 + j;
                    const bool mneg = (offdiag || (li < lj)) && (ca[fa * 4 + j] != cb);
                    float s = v[j];
                    s = fminf(fmaxf(s, -CLIPV), CLIPV);
                    float uu = (s + CLIPV) * INVSTEP;
                    int jb = (int)uu;
                    if (jb > 98) jb = 98;
                    float w_hi = uu - (float)jb;
                    float2 cd = crep2[jb];
                    float mm = mneg ? 1.0f : 0.0f;
                    lacc = fmaf(mm, fmaf(w_hi, cd.y, cd.x), lacc);
                    lcnt += mm;
                }
            }
        }
    }
    #undef STAGE_UNIT

    #pragma unroll
    for (int off = 32; off > 0; off >>= 1) {
        lacc += __shfl_xor(lacc, off);
        lcnt += __shfl_xor(lcnt, off);
    }
    if (lane == 0) { red[wid] = lacc; red[4 + wid] = lcnt; }
    __syncthreads();
    if (tid == 0) {
        float L = red[0] + red[1] + red[2] + red[3];
        float C = red[4] + red[5] + red[6] + red[7];
        faddf(&gLoss[blockIdx.x & 31], L);
        faddf(&gCnt[blockIdx.x & 31], C);
        __threadfence();
        unsigned int tk = atomicAdd(gDone, 1u);
        if (tk == NBLK - 1) {
            __threadfence();
            float ls = 0.f, cs = 0.f;
            for (int i = 0; i < 32; ++i) {
                ls += __hip_atomic_load(&gLoss[i], __ATOMIC_RELAXED, __HIP_MEMORY_SCOPE_AGENT);
                cs += __hip_atomic_load(&gCnt[i], __ATOMIC_RELAXED, __HIP_MEMORY_SCOPE_AGENT);
            }
            out[0] = ls / cs;            // cdf already contains 1/sp
        }
    }
}

extern "C" void kernel_launch(void* const* d_in, const int* in_sizes, int n_in,
                              void* d_out, int out_size, void* d_ws, size_t ws_size,
                              hipStream_t stream) {
    const float* emb = (const float*)d_in[0];
    const int* classes = (const int*)d_in[1];
    float* out = (float*)d_out;

    ushort* nemb = (ushort*)d_ws;                                   // 1 MB
    float* ctl = (float*)((char*)d_ws + (size_t)BN * DD * sizeof(ushort));
    float* gPos = ctl;                                // 100
    float* gLoss = gPos + NSTEPS;                     // 32
    float* gCnt = gLoss + 32;                         // 32
    unsigned int* gDone = (unsigned int*)(gCnt + 32); // 1
    unsigned int* gDoneP = gDone + 1;                 // 1
    float* gCdf = (float*)(gDoneP + 1);               // 100 (fully written)

    hl_normalize<<<BN / 4, 256, 0, stream>>>(emb, nemb, ctl);
    hl_poscls<<<NSTEPS, 256, 0, stream>>>(nemb, classes, gPos, gDoneP, gCdf);
    hl_neg<<<NBLK, 256, 0, stream>>>(nemb, classes, gCdf, gLoss, gCnt, gDone, out);
}

// Round 33
// 42.009 us; speedup vs baseline: 1.0415x; 1.0415x over previous
//
#include <hip/hip_runtime.h>
#include <hip/hip_bf16.h>
#include <cstddef>

#define BN 4096
#define DD 128
#define NSTEPS 100
#define PTILE 128
#define PLSTR 136   // poscls LDS row stride (padded)
#define GRID_T 32
#define NOFF 496    // strictly-upper tile pairs (ti<tj)
#define NBLK 264    // neg: 2 units per block (528 units)
#define NREPH 16
#define NREPC2 8    // cdf float2 replicas (stride 101)

typedef __attribute__((ext_vector_type(8))) short bf16x8;
typedef __attribute__((ext_vector_type(4))) float f32x4;

__device__ __forceinline__ void faddf(float* p, float v) { unsafeAtomicAdd(p, v); }

// ws ctl: gPos[100] gLoss[32] gCnt[32] gDone gDoneP  (166 words) | gCdf[100]
#define ZERON 166

// ---------------- normalize + convert to bf16 + zero control block ----------------
__global__ __launch_bounds__(256) void hl_normalize(const float* __restrict__ emb,
                                                    ushort* __restrict__ out,
                                                    float* __restrict__ zero_blk) {
    if (blockIdx.x == 0 && threadIdx.x < ZERON) zero_blk[threadIdx.x] = 0.f;
    int w = threadIdx.x >> 6;
    int lane = threadIdx.x & 63;
    int row = (blockIdx.x << 2) + w;
    const float2 v = *(const float2*)(emb + (size_t)row * DD + 2 * lane);
    float ss = v.x * v.x + v.y * v.y;
    #pragma unroll
    for (int off = 32; off > 0; off >>= 1) ss += __shfl_xor(ss, off);
    float inv = 1.0f / sqrtf(ss);
    __hip_bfloat16 b0 = __float2bfloat16(v.x * inv);
    __hip_bfloat16 b1 = __float2bfloat16(v.y * inv);
    ushort2 pk;
    pk.x = *(ushort*)&b0;
    pk.y = *(ushort*)&b1;
    *(ushort2*)(out + (size_t)row * DD + 2 * lane) = pk;
}

// ---------------- POS histogram: per-class MFMA gram; last block builds cdf ----------
__global__ __launch_bounds__(256) void hl_poscls(const ushort* __restrict__ nemb,
                                                 const int* __restrict__ cls,
                                                 float* __restrict__ gPos,
                                                 unsigned int* __restrict__ gDoneP,
                                                 float* __restrict__ gCdf) {
    const int c = blockIdx.x;
    __shared__ int idx[256];
    __shared__ int scan[256];
    __shared__ ushort As[64 * PLSTR];
    __shared__ ushort Bs[64 * PLSTR];
    __shared__ float hpos[NREPH * 101];
    __shared__ int mTot;
    __shared__ int lastFlag;
    const int tid = threadIdx.x;

    for (int i = tid; i < NREPH * 101; i += 256) hpos[i] = 0.f;

    // deterministic compaction: thread t owns elements [16t, 16t+16)
    const int base = tid * 16;
    int myCnt = 0;
    #pragma unroll
    for (int k = 0; k < 16; ++k) myCnt += (cls[base + k] == c);
    scan[tid] = myCnt;
    __syncthreads();
    for (int s = 1; s < 256; s <<= 1) {
        int v = (tid >= s) ? scan[tid - s] : 0;
        __syncthreads();
        scan[tid] += v;
        __syncthreads();
    }
    int w = scan[tid] - myCnt;
    if (tid == 255) mTot = scan[255] > 256 ? 256 : scan[255];
    #pragma unroll
    for (int k = 0; k < 16; ++k) {
        if (cls[base + k] == c && w < 256) { idx[w] = base + k; ++w; }
    }
    __syncthreads();
    const int m = mTot;
    const int nt = (m + 63) >> 6;

    constexpr float INVSTEP = 49.5f;
    constexpr float CLIPV = 1.0f - 1e-6f;

    const int lane = tid & 63;
    const int wv = tid >> 6;
    const int lr = lane & 15;
    const int kg = lane >> 4;
    const int rep = (lane & 15) * 101;

    for (int si = 0; si < nt; ++si) {
        for (int sj = si; sj < nt; ++sj) {
            __syncthreads();
            #pragma unroll
            for (int it = 0; it < 4; ++it) {
                int q = it * 256 + tid;
                int row = q >> 4;
                int ch = q & 15;
                int ga = si * 64 + row;
                int gb = sj * 64 + row;
                int ra = idx[ga < m ? ga : 0];
                int rb = idx[gb < m ? gb : 0];
                *(float4*)(&As[row * PLSTR + ch * 8]) =
                    *(const float4*)(nemb + (size_t)ra * DD + ch * 8);
                *(float4*)(&Bs[row * PLSTR + ch * 8]) =
                    *(const float4*)(nemb + (size_t)rb * DD + ch * 8);
            }
            __syncthreads();

            f32x4 zero4 = {0.f, 0.f, 0.f, 0.f};
            f32x4 pacc[4] = {zero4, zero4, zero4, zero4};
            #pragma unroll
            for (int ks = 0; ks < 4; ++ks) {
                bf16x8 af = *(const bf16x8*)(&As[(wv * 16 + lr) * PLSTR + ks * 32 + kg * 8]);
                #pragma unroll
                for (int fb = 0; fb < 4; ++fb) {
                    bf16x8 bf = *(const bf16x8*)(&Bs[(fb * 16 + lr) * PLSTR + ks * 32 + kg * 8]);
                    pacc[fb] = __builtin_amdgcn_mfma_f32_16x16x32_bf16(af, bf, pacc[fb], 0, 0, 0);
                }
            }

            #pragma unroll
            for (int fb = 0; fb < 4; ++fb) {
                const int gb = sj * 64 + fb * 16 + lr;
                #pragma unroll
                for (int j = 0; j < 4; ++j) {
                    const int ga = si * 64 + wv * 16 + kg * 4 + j;
                    if (ga < gb && gb < m) {
                        float s = pacc[fb][j];
                        s = fminf(fmaxf(s, -CLIPV), CLIPV);
                        float u = (s + CLIPV) * INVSTEP;
                        int jb = (int)u;
                        if (jb > 98) jb = 98;
                        float w_hi = u - (float)jb;
                        float w_lo = 1.0f - w_hi;
                        faddf(&hpos[rep + jb], w_lo);
                        faddf(&hpos[rep + jb + 1], w_hi);
                    }
                }
            }
        }
    }
    __syncthreads();
    if (tid < NSTEPS) {
        float v = 0.f;
        #pragma unroll
        for (int r = 0; r < NREPH; ++r) v += hpos[r * 101 + tid];
        if (v != 0.f) faddf(&gPos[tid], v);
    }
    __threadfence();
    if (tid == 0) {
        unsigned int tk = atomicAdd(gDoneP, 1u);
        lastFlag = (tk == NSTEPS - 1);
    }
    __syncthreads();
    if (lastFlag) {
        float v = (tid < NSTEPS)
            ? __hip_atomic_load(&gPos[tid], __ATOMIC_RELAXED, __HIP_MEMORY_SCOPE_AGENT) : 0.f;
        if (tid < 128) hpos[tid] = v;
        __syncthreads();
        for (int off = 1; off < 128; off <<= 1) {
            float x = 0.f;
            if (tid < 128 && tid >= off) x = hpos[tid - off];
            __syncthreads();
            if (tid < 128) hpos[tid] += x;
            __syncthreads();
        }
        const float invsp = 1.0f / hpos[NSTEPS - 1];
        if (tid < NSTEPS) gCdf[tid] = hpos[tid] * invsp;
    }
}

// ---------------- NEG pass: 2-unit software-pipelined MFMA + cdf gather ----------
// stage(u+1) issued after MFMA(u); register epilogue hides the staging flight.
__global__ __launch_bounds__(256, 2) void hl_neg(const ushort* __restrict__ nemb,
                                                 const int* __restrict__ cls,
                                                 const float* __restrict__ gCdf,
                                                 float* __restrict__ gLoss,
                                                 float* __restrict__ gCnt,
                                                 unsigned int* __restrict__ gDone,
                                                 float* __restrict__ out) {
    __shared__ ushort As[PTILE * 128];
    __shared__ ushort Bs[PTILE * 128];
    __shared__ float2 cdf2[NREPC2 * 101];
    __shared__ float red[8];
    __shared__ int clsAb[2][PTILE], clsBb[2][PTILE];

    const int tid = threadIdx.x;
    const int lane = tid & 63;
    const int wid = tid >> 6;
    const int wr = wid >> 1, wc = wid & 1;
    const int lr = lane & 15;
    const int kg = lane >> 4;

    int tiU[2], tjU[2];
    #pragma unroll
    for (int u = 0; u < 2; ++u) {
        int id = blockIdx.x * 2 + u;
        if (id < NOFF) {
            int ti = 0, rem = id;
            while (rem >= GRID_T - 1 - ti) { rem -= GRID_T - 1 - ti; ++ti; }
            tiU[u] = ti; tjU[u] = ti + 1 + rem;
        } else {
            tiU[u] = tjU[u] = id - NOFF;
        }
    }

    for (int i = tid; i < NREPC2 * NSTEPS; i += 256) {
        int r = i / NSTEPS, b = i - r * NSTEPS;
        float c0 = gCdf[b];
        float c1 = gCdf[(b < NSTEPS - 1) ? b + 1 : NSTEPS - 1];
        float2 cd; cd.x = c0; cd.y = c1 - c0;
        cdf2[r * 101 + b] = cd;
    }

    constexpr float INVSTEP = 49.5f;
    constexpr float CLIPV = 1.0f - 1e-6f;
    const float2* crep2 = &cdf2[(lane & 7) * 101];
    const int li_base = wr * 64 + (kg << 2);
    const int lj_base = wc * 64 + lr;

    float lacc = 0.f, lcnt = 0.f;
    const int rloc = lane >> 4;
    const int pch = lane & 15;

    #define STAGE_UNIT(U)                                                            \
    {                                                                                \
        const int ti_ = tiU[U], tj_ = tjU[U];                                        \
        const bool dg_ = (ti_ == tj_);                                               \
        if (tid < PTILE) clsAb[(U) & 1][tid] = cls[ti_ * PTILE + tid];               \
        else             clsBb[(U) & 1][tid - PTILE] = cls[tj_ * PTILE + (tid - PTILE)]; \
        const ushort* Ag_ = nemb + (size_t)(ti_ * PTILE) * DD;                       \
        const ushort* Bg_ = nemb + (size_t)(tj_ * PTILE) * DD;                       \
        _Pragma("unroll")                                                            \
        for (int t = 0; t < 8; ++t) {                                                \
            int row = wid * 32 + t * 4 + rloc;                                       \
            int lch = pch ^ (row & 7);                                               \
            const ushort* ga = Ag_ + (size_t)row * DD + lch * 8;                     \
            ushort* la = &As[(wid * 32 + t * 4) * 128];                              \
            __builtin_amdgcn_global_load_lds(                                        \
                (const __attribute__((address_space(1))) void*)ga,                   \
                (__attribute__((address_space(3))) void*)la, 16, 0, 0);              \
        }                                                                            \
        if (!dg_) {                                                                  \
            _Pragma("unroll")                                                        \
            for (int t = 0; t < 8; ++t) {                                            \
                int row = wid * 32 + t * 4 + rloc;                                   \
                int lch = pch ^ (row & 7);                                           \
                const ushort* gb = Bg_ + (size_t)row * DD + lch * 8;                 \
                ushort* lb = &Bs[(wid * 32 + t * 4) * 128];                          \
                __builtin_amdgcn_global_load_lds(                                    \
                    (const __attribute__((address_space(1))) void*)gb,               \
                    (__attribute__((address_space(3))) void*)lb, 16, 0, 0);          \
            }                                                                        \
        }                                                                            \
    }

    STAGE_UNIT(0);

    #pragma unroll
    for (int u = 0; u < 2; ++u) {
        const bool diag = (tiU[u] == tjU[u]);

        __syncthreads();

        const ushort* Bsel = diag ? As : Bs;

        f32x4 zero4 = {0.f, 0.f, 0.f, 0.f};
        f32x4 acc[4][4];
        #pragma unroll
        for (int a = 0; a < 4; ++a)
            #pragma unroll
            for (int b = 0; b < 4; ++b) acc[a][b] = zero4;

        #pragma unroll
        for (int ks = 0; ks < 4; ++ks) {
            bf16x8 af[4], bfr[4];
            #pragma unroll
            for (int f = 0; f < 4; ++f) {
                int arow = wr * 64 + f * 16 + lr;
                int pca = ((ks << 2) | kg) ^ (arow & 7);
                af[f] = *(const bf16x8*)(&As[arow * 128 + pca * 8]);
                int brow = wc * 64 + f * 16 + lr;
                int pcb = ((ks << 2) | kg) ^ (brow & 7);
                bfr[f] = *(const bf16x8*)(&Bsel[brow * 128 + pcb * 8]);
            }
            #pragma unroll
            for (int fa = 0; fa < 4; ++fa)
                #pragma unroll
                for (int fb = 0; fb < 4; ++fb)
                    acc[fa][fb] = __builtin_amdgcn_mfma_f32_16x16x32_bf16(af[fa], bfr[fb], acc[fa][fb], 0, 0, 0);
        }

        __syncthreads();

        if (u == 0) STAGE_UNIT(1);

        const int* clsA_ = clsAb[u & 1];
        const int* clsB_ = diag ? clsAb[u & 1] : clsBb[u & 1];
        const bool offdiag = !diag;

        int ca[16];
        #pragma unroll
        for (int fa = 0; fa < 4; ++fa)
            #pragma unroll
            for (int j = 0; j < 4; ++j) ca[fa * 4 + j] = clsA_[li_base + fa * 16 + j];

        #pragma unroll
        for (int fb = 0; fb < 4; ++fb) {
            const int lj = lj_base + fb * 16;
            const int cb = clsB_[lj];
            #pragma unroll
            for (int fa = 0; fa < 4; ++fa) {
                const int li0 = li_base + fa * 16;
                f32x4 v = acc[fa][fb];
                #pragma unroll
                for (int j = 0; j < 4; ++j) {
                    const int li = li0 + j;
                    const bool mneg = (offdiag || (li < lj)) && (ca[fa * 4 + j] != cb);
                    float s = v[j];
                    s = fminf(fmaxf(s, -CLIPV), CLIPV);
                    float uu = (s + CLIPV) * INVSTEP;
                    int jb = (int)uu;
                    if (jb > 98) jb = 98;
                    float w_hi = uu - (float)jb;
                    float2 cd = crep2[jb];
                    float mm = mneg ? 1.0f : 0.0f;
                    lacc = fmaf(mm, fmaf(w_hi, cd.y, cd.x), lacc);
                    lcnt += mm;
                }
            }
        }
    }
    #undef STAGE_UNIT

    #pragma unroll
    for (int off = 32; off > 0; off >>= 1) {
        lacc += __shfl_xor(lacc, off);
        lcnt += __shfl_xor(lcnt, off);
    }
    if (lane == 0) { red[wid] = lacc; red[4 + wid] = lcnt; }
    __syncthreads();
    if (tid == 0) {
        float L = red[0] + red[1] + red[2] + red[3];
        float C = red[4] + red[5] + red[6] + red[7];
        faddf(&gLoss[blockIdx.x & 31], L);
        faddf(&gCnt[blockIdx.x & 31], C);
        __threadfence();
        unsigned int tk = atomicAdd(gDone, 1u);
        if (tk == NBLK - 1) {
            __threadfence();
            float ls = 0.f, cs = 0.f;
            for (int i = 0; i < 32; ++i) {
                ls += __hip_atomic_load(&gLoss[i], __ATOMIC_RELAXED, __HIP_MEMORY_SCOPE_AGENT);
                cs += __hip_atomic_load(&gCnt[i], __ATOMIC_RELAXED, __HIP_MEMORY_SCOPE_AGENT);
            }
            out[0] = ls / cs;            // cdf already contains 1/sp
        }
    }
}

extern "C" void kernel_launch(void* const* d_in, const int* in_sizes, int n_in,
                              void* d_out, int out_size, void* d_ws, size_t ws_size,
                              hipStream_t stream) {
    const float* emb = (const float*)d_in[0];
    const int* classes = (const int*)d_in[1];
    float* out = (float*)d_out;

    ushort* nemb = (ushort*)d_ws;                                   // 1 MB
    float* ctl = (float*)((char*)d_ws + (size_t)BN * DD * sizeof(ushort));
    float* gPos = ctl;                                // 100
    float* gLoss = gPos + NSTEPS;                     // 32
    float* gCnt = gLoss + 32;                         // 32
    unsigned int* gDone = (unsigned int*)(gCnt + 32); // 1
    unsigned int* gDoneP = gDone + 1;                 // 1
    float* gCdf = (float*)(gDoneP + 1);               // 100 (fully written)

    hl_normalize<<<BN / 4, 256, 0, stream>>>(emb, nemb, ctl);
    hl_poscls<<<NSTEPS, 256, 0, stream>>>(nemb, classes, gPos, gDoneP, gCdf);
    hl_neg<<<NBLK, 256, 0, stream>>>(nemb, classes, gCdf, gLoss, gCnt, gDone, out);
}